// Round 6
// baseline (140.101 us; speedup 1.0000x reference)
//
#include <hip/hip_runtime.h>
#include <hip/hip_cooperative_groups.h>
#include <math.h>

namespace cg = cooperative_groups;

// nf1 box-inclusion loss — round 6: ONE cooperative dispatch with coalesced
// phase A + LDS byte-table screen.
//
// Timing decomposition (rounds 0-5): dur ~= fill(43, harness ws re-poison,
// stream-serialized) + kernels + ~8us/extra-dispatch gap.
//   R3: 43 + 44(coop fused, bad phase A) + 0  = 87  ✓
//   R2: 43 + 82(two kernels)            + 17 = 142 ✓
//   R4/5: 43 + kernels + 15 = 87  => kernels ~25-30us.
// Lever: single coop dispatch (gap~0, proven R0/R3) + R4's coalesced tile
// phase A (R3's fused lost ~16us to 200B-strided scalar phase A).
//
// fused3: 256 blocks x 1024 thr, 100 KB dyn LDS -> exactly 1 block/CU
// (LDS 100<160 KB, 16<32 waves, VGPR fine) => co-residency guaranteed,
// hardcoded coop grid safe; launch failure falls back to two-kernel path.
//
// Exactness (absmax 0.0, rounds 0/3/4/5, identical math):
//  - byte bucket (k=255, width 16, sentinel 255) conservative for ANY data;
//  - bucket mismatch => dim-0 disjoint => loss == 1.0 exactly;
//  - bucket match (~1.2%) => exact fp32 dim-0 key test (same ops as ref);
//  - key pass (~2e-4) => full 25-dim reference math.

#define DIMS 25
#define EMB_BOUND 10000.0f
#define FBLK 1024
#define FTROWS 256
#define TILE_BYTES (FTROWS * 2 * DIMS * 4)   // 51200 B
#define TROWS 128
#define TFLOATS (TROWS * 2 * DIMS)

// ---------------- ultimate fallback (exact, no assumptions) ------------------
__global__ void init_ws_kernel(float* ws) {
    if (threadIdx.x == 0 && blockIdx.x == 0) ws[0] = 0.0f;
}

__global__ __launch_bounds__(256, 8) void nf1_fallback_kernel(
    const float* __restrict__ emb, const int2* __restrict__ pairs,
    int n_pairs, float* __restrict__ ws)
{
    const int gl  = threadIdx.x & 31;
    const int gid = blockIdx.x * (blockDim.x >> 5) + (threadIdx.x >> 5);
    const int ngrp = gridDim.x * (blockDim.x >> 5);
    float acc = 0.0f;
    for (int p = gid; p < n_pairs; p += ngrp) {
        int2 pr = pairs[p];
        const float* rc = emb + (size_t)pr.x * (2 * DIMS);
        const float* rd = emb + (size_t)pr.y * (2 * DIMS);
        float t = 1.0f, a = 1.0f;
        if (gl < DIMS) {
            float cc = rc[gl], co = fabsf(rc[DIMS + gl]);
            float dc = rd[gl], dd = fabsf(rd[DIMS + gl]);
            float lo = fmaxf(cc - co, dc - dd);
            float hi = fminf(cc + co, dc + dd);
            t = fmaxf(hi - lo, 0.0f);
            a = 2.0f * co;
        }
        #pragma unroll
        for (int m = 16; m >= 1; m >>= 1) { t *= __shfl_xor(t, m, 32); a *= __shfl_xor(a, m, 32); }
        float loss;
        if (a == 0.0f)     loss = 0.0f;
        else if (isinf(a)) loss = 1.0f - t / (2.0f * EMB_BOUND);
        else               loss = 1.0f - t / a;
        loss = fmaxf(loss, 0.0f);
        if (gl == 0) acc += loss * loss;
    }
    #pragma unroll
    for (int m = 32; m >= 1; m >>= 1) acc += __shfl_xor(acc, m, 64);
    __shared__ float wsum[4];
    if ((threadIdx.x & 63) == 0) wsum[threadIdx.x >> 6] = acc;
    __syncthreads();
    if (threadIdx.x == 0) atomicAdd(ws, wsum[0] + wsum[1] + wsum[2] + wsum[3]);
}

__global__ void fallback_finalize_kernel(const float* __restrict__ ws, float* __restrict__ out) {
    if (threadIdx.x == 0 && blockIdx.x == 0) out[0] = sqrtf(fmaxf(ws[0], 0.0f));
}

// ---------------- shared helpers --------------------------------------------
__device__ __forceinline__ float slow_pair(const float* __restrict__ emb, int2 pr) {
    const float* ra = emb + (size_t)pr.x * (2 * DIMS);
    const float* rb = emb + (size_t)pr.y * (2 * DIMS);
    float inter = 1.0f, carea = 1.0f;
    for (int j = 0; j < DIMS; j++) {
        float cc = ra[j], co = fabsf(ra[DIMS + j]);
        float dc = rb[j], dd = fabsf(rb[DIMS + j]);
        float lo = fmaxf(cc - co, dc - dd);
        float hi = fminf(cc + co, dc + dd);
        inter *= fmaxf(hi - lo, 0.0f);
        carea *= 2.0f * co;
    }
    float loss;
    if (carea == 0.0f)     loss = 0.0f;
    else if (isinf(carea)) loss = 1.0f - inter / (2.0f * EMB_BOUND);
    else                   loss = 1.0f - inter / carea;
    loss = fmaxf(loss, 0.0f);
    return loss * loss;
}

__device__ __forceinline__ float key_pair(const float2* __restrict__ keys,
                                          const float* __restrict__ emb, int2 pr) {
    float2 ka = keys[pr.x];
    float2 kb = keys[pr.y];
    float t0 = fminf(ka.y, kb.y) - fmaxf(ka.x, kb.x);   // exact reference dim-0
    if (t0 > 0.0f) return slow_pair(emb, pr);
    return 1.0f;                                         // loss == 1 exactly
}

template <int K>
__device__ __forceinline__ int ring_bucket(float lo, float hi) {
    float w = hi - lo;
    if (w <= 16.0f && fabsf(lo) <= 1.0e6f) {             // NaN -> sentinel
        int i = (int)floorf(lo * 0.0625f);               // width 16, exact
        int b = i % K; if (b < 0) b += K;
        return b;
    }
    return K;                                            // sentinel: always pass
}

__device__ __forceinline__ bool ring_pass(unsigned a, unsigned b, unsigned K) {
    unsigned dd = (a >= b) ? (a - b) : (b - a);
    return (a == K) | (b == K) | (dd <= 1u) | (dd == K - 1u);
}

// ---------------- fused3: single cooperative dispatch ------------------------
__global__ __launch_bounds__(FBLK, 1) void fused3_kernel(
    const float* __restrict__ emb, float2* __restrict__ keys,
    unsigned char* __restrict__ gbuck, const int2* __restrict__ pairs,
    int n_pairs, int n_rows, float* __restrict__ acc,
    unsigned* __restrict__ ticket, float* __restrict__ out)
{
    extern __shared__ unsigned char smem[];   // aliased: phase-A tile | sbuck
    __shared__ float wsum[FBLK / 64];
    const int nthreads = gridDim.x * blockDim.x;
    const int t = blockIdx.x * blockDim.x + threadIdx.x;
    if (t == 0) { acc[0] = 0.0f; ticket[0] = 0u; }

    // ---- phase A: coalesced tile repack (FTROWS rows / 51.2 KB per tile) ----
    {
        float* tile = (float*)smem;
        const int n_tiles = (n_rows + FTROWS - 1) / FTROWS;
        for (int tIdx = blockIdx.x; tIdx < n_tiles; tIdx += gridDim.x) {
            const int r0 = tIdx * FTROWS;
            const int rows = min(FTROWS, n_rows - r0);
            const int cnt = rows * (2 * DIMS);
            const int n4 = cnt >> 2;
            {
                const float4* g4 = (const float4*)(emb + (size_t)r0 * (2 * DIMS));
                float4* s4 = (float4*)tile;
                for (int i = threadIdx.x; i < n4; i += blockDim.x) s4[i] = g4[i];
                for (int i = (n4 << 2) + threadIdx.x; i < cnt; i += blockDim.x)
                    tile[i] = emb[(size_t)r0 * (2 * DIMS) + i];
            }
            __syncthreads();
            for (int j = threadIdx.x; j < rows; j += blockDim.x) {
                float c = tile[j * (2 * DIMS)];
                float o = fabsf(tile[j * (2 * DIMS) + DIMS]);
                float lo = c - o, hi = c + o;            // same fp32 ops as ref
                keys[r0 + j] = make_float2(lo, hi);
                gbuck[r0 + j] = (unsigned char)ring_bucket<255>(lo, hi);
            }
            __syncthreads();
        }
    }

    // prefetch first oct's pairs: HBM round-trip overlaps grid.sync+broadcast
    const int noct = n_pairs >> 3;
    const int4* p4 = (const int4*)pairs;
    int4 qa, qb, qc, qd;
    if (t < noct) {
        qa = p4[4 * t + 0]; qb = p4[4 * t + 1];
        qc = p4[4 * t + 2]; qd = p4[4 * t + 3];
    }

    cg::this_grid().sync();

    // ---- phase B: broadcast byte table to LDS, then screen ----
    unsigned char* sbuck = smem;
    {
        const int nb16 = (n_rows + 15) >> 4;
        const uint4* g4 = (const uint4*)gbuck;
        uint4* s4 = (uint4*)sbuck;
        for (int i = threadIdx.x; i < nb16; i += blockDim.x) s4[i] = g4[i];
    }
    __syncthreads();

    float sum = 0.0f;
    for (int q = t; q < noct; q += nthreads) {
        if (q != t) {
            qa = p4[4 * q + 0]; qb = p4[4 * q + 1];
            qc = p4[4 * q + 2]; qd = p4[4 * q + 3];
        }
        int2 pr[8] = { make_int2(qa.x, qa.y), make_int2(qa.z, qa.w),
                       make_int2(qb.x, qb.y), make_int2(qb.z, qb.w),
                       make_int2(qc.x, qc.y), make_int2(qc.z, qc.w),
                       make_int2(qd.x, qd.y), make_int2(qd.z, qd.w) };
        unsigned ba[8], bb[8];
        #pragma unroll
        for (int i = 0; i < 8; i++) { ba[i] = sbuck[pr[i].x]; bb[i] = sbuck[pr[i].y]; }
        #pragma unroll
        for (int i = 0; i < 8; i++) {
            if (ring_pass(ba[i], bb[i], 255u)) sum += key_pair(keys, emb, pr[i]); // ~1.2%
            else                               sum += 1.0f;   // certain-disjoint
        }
    }
    for (int p = (noct << 3) + t; p < n_pairs; p += nthreads) {
        int2 pr = pairs[p];
        unsigned a = sbuck[pr.x], b = sbuck[pr.y];
        if (ring_pass(a, b, 255u)) sum += key_pair(keys, emb, pr);
        else                       sum += 1.0f;
    }

    #pragma unroll
    for (int m = 32; m >= 1; m >>= 1) sum += __shfl_xor(sum, m, 64);
    if ((threadIdx.x & 63) == 0) wsum[threadIdx.x >> 6] = sum;
    __syncthreads();
    if (threadIdx.x == 0) {
        float s = 0.0f;
        #pragma unroll
        for (int w = 0; w < FBLK / 64; w++) s += wsum[w];
        atomicAdd(acc, s);
        __threadfence();
        unsigned tk = atomicAdd(ticket, 1u);
        if (tk == gridDim.x - 1)
            out[0] = sqrtf(fmaxf(atomicAdd(acc, 0.0f), 0.0f));
    }
}

// ---------------- two-kernel fallback (proven round 4/5) ---------------------
__global__ __launch_bounds__(256) void repack_tile_kernel(
    const float* __restrict__ emb, float2* __restrict__ keys,
    unsigned char* __restrict__ gbuck, int n_rows,
    float* __restrict__ acc, unsigned* __restrict__ ticket)
{
    __shared__ float tile[TFLOATS];
    if (blockIdx.x == 0 && threadIdx.x == 0) { acc[0] = 0.0f; ticket[0] = 0u; }
    const int n_tiles = (n_rows + TROWS - 1) / TROWS;
    for (int tIdx = blockIdx.x; tIdx < n_tiles; tIdx += gridDim.x) {
        const int r0 = tIdx * TROWS;
        const int rows = min(TROWS, n_rows - r0);
        const int cnt = rows * (2 * DIMS);
        const int n4 = cnt >> 2;
        {
            const float4* g4 = (const float4*)(emb + (size_t)r0 * (2 * DIMS));
            float4* s4 = (float4*)tile;
            for (int i = threadIdx.x; i < n4; i += blockDim.x) s4[i] = g4[i];
            for (int i = (n4 << 2) + threadIdx.x; i < cnt; i += blockDim.x)
                tile[i] = emb[(size_t)r0 * (2 * DIMS) + i];
        }
        __syncthreads();
        for (int j = threadIdx.x; j < rows; j += blockDim.x) {
            float c = tile[j * (2 * DIMS)];
            float o = fabsf(tile[j * (2 * DIMS) + DIMS]);
            float lo = c - o, hi = c + o;
            keys[r0 + j] = make_float2(lo, hi);
            gbuck[r0 + j] = (unsigned char)ring_bucket<255>(lo, hi);
        }
        __syncthreads();
    }
}

__global__ __launch_bounds__(FBLK, 1) void screen_byte_kernel(
    const float2* __restrict__ keys, const unsigned char* __restrict__ gbuck,
    const float* __restrict__ emb, const int2* __restrict__ pairs,
    int n_pairs, int n_rows, float* __restrict__ acc,
    unsigned* __restrict__ ticket, float* __restrict__ out)
{
    extern __shared__ unsigned char sbuck[];
    __shared__ float wsum[FBLK / 64];
    const int nthreads = gridDim.x * blockDim.x;
    const int t = blockIdx.x * blockDim.x + threadIdx.x;
    const int noct = n_pairs >> 3;
    const int4* p4 = (const int4*)pairs;

    int4 qa, qb, qc, qd;
    if (t < noct) {
        qa = p4[4 * t + 0]; qb = p4[4 * t + 1];
        qc = p4[4 * t + 2]; qd = p4[4 * t + 3];
    }
    {
        const int nb16 = (n_rows + 15) >> 4;
        const uint4* g4 = (const uint4*)gbuck;
        uint4* s4 = (uint4*)sbuck;
        for (int i = threadIdx.x; i < nb16; i += blockDim.x) s4[i] = g4[i];
    }
    __syncthreads();

    float sum = 0.0f;
    for (int q = t; q < noct; q += nthreads) {
        if (q != t) {
            qa = p4[4 * q + 0]; qb = p4[4 * q + 1];
            qc = p4[4 * q + 2]; qd = p4[4 * q + 3];
        }
        int2 pr[8] = { make_int2(qa.x, qa.y), make_int2(qa.z, qa.w),
                       make_int2(qb.x, qb.y), make_int2(qb.z, qb.w),
                       make_int2(qc.x, qc.y), make_int2(qc.z, qc.w),
                       make_int2(qd.x, qd.y), make_int2(qd.z, qd.w) };
        unsigned ba[8], bb[8];
        #pragma unroll
        for (int i = 0; i < 8; i++) { ba[i] = sbuck[pr[i].x]; bb[i] = sbuck[pr[i].y]; }
        #pragma unroll
        for (int i = 0; i < 8; i++) {
            if (ring_pass(ba[i], bb[i], 255u)) sum += key_pair(keys, emb, pr[i]);
            else                               sum += 1.0f;
        }
    }
    for (int p = (noct << 3) + t; p < n_pairs; p += nthreads) {
        int2 pr = pairs[p];
        unsigned a = sbuck[pr.x], b = sbuck[pr.y];
        if (ring_pass(a, b, 255u)) sum += key_pair(keys, emb, pr);
        else                       sum += 1.0f;
    }

    #pragma unroll
    for (int m = 32; m >= 1; m >>= 1) sum += __shfl_xor(sum, m, 64);
    if ((threadIdx.x & 63) == 0) wsum[threadIdx.x >> 6] = sum;
    __syncthreads();
    if (threadIdx.x == 0) {
        float s = 0.0f;
        #pragma unroll
        for (int w = 0; w < FBLK / 64; w++) s += wsum[w];
        atomicAdd(acc, s);
        __threadfence();
        unsigned tk = atomicAdd(ticket, 1u);
        if (tk == gridDim.x - 1)
            out[0] = sqrtf(fmaxf(atomicAdd(acc, 0.0f), 0.0f));
    }
}

extern "C" void kernel_launch(void* const* d_in, const int* in_sizes, int n_in,
                              void* d_out, int out_size, void* d_ws, size_t ws_size,
                              hipStream_t stream) {
    const float* emb  = (const float*)d_in[0];     // (100000, 50) fp32
    const int2*  prs  = (const int2*)d_in[1];      // (2000000, 2) int32
    int n_pairs = in_sizes[1] / 2;
    int n_rows  = in_sizes[0] / (2 * DIMS);

    float*    ws     = (float*)d_ws;                // ws[0]=acc, ws[1]=ticket
    unsigned* ticket = (unsigned*)(ws + 1);
    float*    out    = (float*)d_out;
    float2*   keys   = (float2*)((char*)d_ws + 256);            // 8B * n_rows
    unsigned char* gbuck = (unsigned char*)(keys + n_rows);     // byte table
    // gbuck byte offset = 256 + 8*n_rows: 16B-aligned for even n_rows.

    const size_t tabBytes = (size_t)((n_rows + 15) & ~15);      // padded table
    const size_t fusedDyn = tabBytes > (size_t)TILE_BYTES ? tabBytes
                                                          : (size_t)TILE_BYTES;
    const bool ws_ok = (ws_size >= 256 + (size_t)n_rows * 8 + tabBytes + 64) &&
                       ((n_rows & 1) == 0);
    const bool byte_ok = ws_ok && (tabBytes + 512 <= 160 * 1024);

    bool launched = false;
    if (byte_ok && (fusedDyn + 512 <= 160 * 1024)) {
        // 1 block/CU co-residency guaranteed by construction (100 KB LDS,
        // 16 waves, 64 VGPR) -> hardcoded 256-block coop grid is safe.
        void* args[] = { (void*)&emb, (void*)&keys, (void*)&gbuck,
                         (void*)&prs, (void*)&n_pairs, (void*)&n_rows,
                         (void*)&ws, (void*)&ticket, (void*)&out };
        hipError_t le = hipLaunchCooperativeKernel(
            (const void*)fused3_kernel, dim3(256), dim3(FBLK),
            args, (unsigned int)fusedDyn, stream);
        if (le == hipSuccess) launched = true;
    }

    if (!launched && byte_ok) {
        const int n_tiles = (n_rows + TROWS - 1) / TROWS;
        hipLaunchKernelGGL(repack_tile_kernel, dim3(min(n_tiles, 2048)), dim3(256),
                           0, stream, emb, keys, gbuck, n_rows, ws, ticket);
        hipLaunchKernelGGL(screen_byte_kernel, dim3(256), dim3(FBLK),
                           tabBytes, stream,
                           keys, gbuck, emb, prs, n_pairs, n_rows, ws, ticket, out);
        launched = true;
    }

    if (!launched) {
        hipLaunchKernelGGL(init_ws_kernel, dim3(1), dim3(64), 0, stream, ws);
        hipLaunchKernelGGL(nf1_fallback_kernel, dim3(4096), dim3(256), 0, stream,
                           emb, prs, n_pairs, ws);
        hipLaunchKernelGGL(fallback_finalize_kernel, dim3(1), dim3(64), 0, stream, ws, out);
    }
}

// Round 7
// 94.064 us; speedup vs baseline: 1.4894x; 1.4894x over previous
//
#include <hip/hip_runtime.h>
#include <math.h>

// nf1 box-inclusion loss — round 7: 6-bit packed bucket table (80 KB LDS)
// => 2 blocks/CU => 32 waves/CU (occupancy 36% -> ~100%).
//
// Evidence: all screen variants are latency-bound with NOTHING saturated
// (VALU 3.5%, HBM 5%, conflicts ~0) at occupancy 36% (100 KB table = 1
// block/CU = 16/32 waves). Component accounting says ~6 us; measured ~25-40.
// The untested structural lever is resident-wave count: halve the table.
//
// 6-bit ring bucket: K=63, width 64 (pow2 -> exact floorf). code = 63
// sentinel (w>64 | |lo|>1e6 | NaN) always passes. Conservative for ANY data:
// non-sentinel ring-distance >= 2  =>  floor(lo/64) differs >= 2  =>
// lo_b >= lo_a + 64 >= lo_a + w_a = hi_a  =>  dim-0 disjoint  =>
// loss == 1.0 exactly (c_area never 0/inf here; absmax 0.0 rounds 0-6).
// Pass rate ~3/63 = 4.8% -> ~190K exact fp32 key tests (same ops as ref),
// of which ~2e-4 of all pairs reach the full 25-dim reference math.
// Packing: 5 codes/u32 (bits 6*(r%5), no straddle): lookup = 1 LDS u32
// read + shift. Table (n_rows+4)/5*4 = 80000 B -> 2x1024-thr blocks/CU
// (160 KB LDS/CU), 512-block grid.

#define DIMS 25
#define EMB_BOUND 10000.0f
#define SBLK 1024
#define TROWS 160                       // 160 rows = 32 pack-words per tile
#define TFLOATS (TROWS * 2 * DIMS)      // 8000 floats = 32 KB

// ---------------- ultimate fallback (exact, no assumptions) ------------------
__global__ void init_ws_kernel(float* ws) {
    if (threadIdx.x == 0 && blockIdx.x == 0) ws[0] = 0.0f;
}

__global__ __launch_bounds__(256, 8) void nf1_fallback_kernel(
    const float* __restrict__ emb, const int2* __restrict__ pairs,
    int n_pairs, float* __restrict__ ws)
{
    const int gl  = threadIdx.x & 31;
    const int gid = blockIdx.x * (blockDim.x >> 5) + (threadIdx.x >> 5);
    const int ngrp = gridDim.x * (blockDim.x >> 5);
    float acc = 0.0f;
    for (int p = gid; p < n_pairs; p += ngrp) {
        int2 pr = pairs[p];
        const float* rc = emb + (size_t)pr.x * (2 * DIMS);
        const float* rd = emb + (size_t)pr.y * (2 * DIMS);
        float t = 1.0f, a = 1.0f;
        if (gl < DIMS) {
            float cc = rc[gl], co = fabsf(rc[DIMS + gl]);
            float dc = rd[gl], dd = fabsf(rd[DIMS + gl]);
            float lo = fmaxf(cc - co, dc - dd);
            float hi = fminf(cc + co, dc + dd);
            t = fmaxf(hi - lo, 0.0f);
            a = 2.0f * co;
        }
        #pragma unroll
        for (int m = 16; m >= 1; m >>= 1) { t *= __shfl_xor(t, m, 32); a *= __shfl_xor(a, m, 32); }
        float loss;
        if (a == 0.0f)     loss = 0.0f;
        else if (isinf(a)) loss = 1.0f - t / (2.0f * EMB_BOUND);
        else               loss = 1.0f - t / a;
        loss = fmaxf(loss, 0.0f);
        if (gl == 0) acc += loss * loss;
    }
    #pragma unroll
    for (int m = 32; m >= 1; m >>= 1) acc += __shfl_xor(acc, m, 64);
    __shared__ float wsum[4];
    if ((threadIdx.x & 63) == 0) wsum[threadIdx.x >> 6] = acc;
    __syncthreads();
    if (threadIdx.x == 0) atomicAdd(ws, wsum[0] + wsum[1] + wsum[2] + wsum[3]);
}

__global__ void fallback_finalize_kernel(const float* __restrict__ ws, float* __restrict__ out) {
    if (threadIdx.x == 0 && blockIdx.x == 0) out[0] = sqrtf(fmaxf(ws[0], 0.0f));
}

// ---------------- shared helpers --------------------------------------------
__device__ __forceinline__ float slow_pair(const float* __restrict__ emb, int2 pr) {
    const float* ra = emb + (size_t)pr.x * (2 * DIMS);
    const float* rb = emb + (size_t)pr.y * (2 * DIMS);
    float inter = 1.0f, carea = 1.0f;
    for (int j = 0; j < DIMS; j++) {
        float cc = ra[j], co = fabsf(ra[DIMS + j]);
        float dc = rb[j], dd = fabsf(rb[DIMS + j]);
        float lo = fmaxf(cc - co, dc - dd);
        float hi = fminf(cc + co, dc + dd);
        inter *= fmaxf(hi - lo, 0.0f);
        carea *= 2.0f * co;
    }
    float loss;
    if (carea == 0.0f)     loss = 0.0f;
    else if (isinf(carea)) loss = 1.0f - inter / (2.0f * EMB_BOUND);
    else                   loss = 1.0f - inter / carea;
    loss = fmaxf(loss, 0.0f);
    return loss * loss;
}

__device__ __forceinline__ float key_pair(const float2* __restrict__ keys,
                                          const float* __restrict__ emb, int2 pr) {
    float2 ka = keys[pr.x];
    float2 kb = keys[pr.y];
    float t0 = fminf(ka.y, kb.y) - fmaxf(ka.x, kb.x);   // exact reference dim-0
    if (t0 > 0.0f) return slow_pair(emb, pr);
    return 1.0f;                                         // loss == 1 exactly
}

__device__ __forceinline__ unsigned ring_bucket6(float lo, float hi) {
    float w = hi - lo;
    if (w <= 64.0f && fabsf(lo) <= 1.0e6f) {             // NaN -> sentinel
        int i = (int)floorf(lo * 0.015625f);             // width 64, exact
        int b = i % 63; if (b < 0) b += 63;
        return (unsigned)b;
    }
    return 63u;                                          // sentinel: always pass
}

__device__ __forceinline__ unsigned lookup6(const unsigned* __restrict__ tab, int idx) {
    int w = idx / 5;                                     // compiler magic-mul
    int r = idx - 5 * w;
    return (tab[w] >> (6 * r)) & 63u;
}

__device__ __forceinline__ bool ring_pass6(unsigned a, unsigned b) {
    unsigned dd = (a >= b) ? (a - b) : (b - a);
    return (a == 63u) | (b == 63u) | (dd <= 1u) | (dd == 62u);
}

// ---------------- kernel 1: tile repack -> keys + packed 6-bit codes ---------
__global__ __launch_bounds__(256) void repack6_kernel(
    const float* __restrict__ emb, float2* __restrict__ keys,
    unsigned* __restrict__ gpack, int n_rows,
    float* __restrict__ acc, unsigned* __restrict__ ticket)
{
    __shared__ float tile[TFLOATS];                      // 32 KB
    __shared__ unsigned char scode[TROWS];
    if (blockIdx.x == 0 && threadIdx.x == 0) { acc[0] = 0.0f; ticket[0] = 0u; }
    const int n_tiles = (n_rows + TROWS - 1) / TROWS;
    for (int tIdx = blockIdx.x; tIdx < n_tiles; tIdx += gridDim.x) {
        const int r0 = tIdx * TROWS;                     // multiple of 160 (=32*5)
        const int rows = min(TROWS, n_rows - r0);
        const int cnt = rows * (2 * DIMS);
        const int n4 = cnt >> 2;
        {
            const float4* g4 = (const float4*)(emb + (size_t)r0 * (2 * DIMS));
            float4* s4 = (float4*)tile;
            for (int i = threadIdx.x; i < n4; i += blockDim.x) s4[i] = g4[i];
            for (int i = (n4 << 2) + threadIdx.x; i < cnt; i += blockDim.x)
                tile[i] = emb[(size_t)r0 * (2 * DIMS) + i];
        }
        __syncthreads();
        for (int j = threadIdx.x; j < rows; j += blockDim.x) {
            float c = tile[j * (2 * DIMS)];
            float o = fabsf(tile[j * (2 * DIMS) + DIMS]);
            float lo = c - o, hi = c + o;                // same fp32 ops as ref
            keys[r0 + j] = make_float2(lo, hi);
            scode[j] = (unsigned char)ring_bucket6(lo, hi);
        }
        __syncthreads();
        const int nwords = (rows + 4) / 5;
        for (int w = threadIdx.x; w < nwords; w += blockDim.x) {
            unsigned word = 0;
            #pragma unroll
            for (int k = 0; k < 5; k++) {
                int j = 5 * w + k;
                unsigned c = (j < rows) ? (unsigned)scode[j] : 63u;  // pad: sentinel
                word |= c << (6 * k);
            }
            gpack[r0 / 5 + w] = word;
        }
        __syncthreads();
    }
}

// ---------------- kernel 2: 6-bit LDS-table screen (2 blocks/CU) -------------
__global__ __launch_bounds__(SBLK) void screen6_kernel(
    const float2* __restrict__ keys, const unsigned* __restrict__ gpack,
    const float* __restrict__ emb, const int2* __restrict__ pairs,
    int n_pairs, int n_rows, float* __restrict__ acc,
    unsigned* __restrict__ ticket, float* __restrict__ out)
{
    extern __shared__ unsigned stab[];                   // packed table, 80 KB
    __shared__ float wsum[SBLK / 64];
    const int nthreads = gridDim.x * blockDim.x;
    const int t = blockIdx.x * blockDim.x + threadIdx.x;
    const int nquad = n_pairs >> 2;
    const int4* p4 = (const int4*)pairs;

    // prefetch first quad: HBM round-trip overlaps the table broadcast
    int4 q0, q1;
    if (t < nquad) { q0 = p4[2 * t]; q1 = p4[2 * t + 1]; }

    {   // coalesced table broadcast (global -> LDS)
        const int nwords = (n_rows + 4) / 5;
        const int n16 = (nwords + 3) >> 2;
        const uint4* g4 = (const uint4*)gpack;
        uint4* s4 = (uint4*)stab;
        for (int i = threadIdx.x; i < n16; i += blockDim.x) s4[i] = g4[i];
    }
    __syncthreads();

    float sum = 0.0f;
    for (int q = t; q < nquad; q += nthreads) {
        if (q != t) { q0 = p4[2 * q]; q1 = p4[2 * q + 1]; }
        int2 pr[4] = { make_int2(q0.x, q0.y), make_int2(q0.z, q0.w),
                       make_int2(q1.x, q1.y), make_int2(q1.z, q1.w) };
        unsigned ba[4], bb[4];
        #pragma unroll
        for (int i = 0; i < 4; i++) { ba[i] = lookup6(stab, pr[i].x); bb[i] = lookup6(stab, pr[i].y); }
        #pragma unroll
        for (int i = 0; i < 4; i++) {
            if (ring_pass6(ba[i], bb[i])) sum += key_pair(keys, emb, pr[i]);  // ~4.8%
            else                          sum += 1.0f;    // certain-disjoint
        }
    }
    for (int p = (nquad << 2) + t; p < n_pairs; p += nthreads) {
        int2 pr = pairs[p];
        unsigned a = lookup6(stab, pr.x), b = lookup6(stab, pr.y);
        if (ring_pass6(a, b)) sum += key_pair(keys, emb, pr);
        else                  sum += 1.0f;
    }

    #pragma unroll
    for (int m = 32; m >= 1; m >>= 1) sum += __shfl_xor(sum, m, 64);
    if ((threadIdx.x & 63) == 0) wsum[threadIdx.x >> 6] = sum;
    __syncthreads();
    if (threadIdx.x == 0) {
        float s = 0.0f;
        #pragma unroll
        for (int w = 0; w < SBLK / 64; w++) s += wsum[w];
        atomicAdd(acc, s);
        __threadfence();
        unsigned tk = atomicAdd(ticket, 1u);
        if (tk == gridDim.x - 1)
            out[0] = sqrtf(fmaxf(atomicAdd(acc, 0.0f), 0.0f));
    }
}

extern "C" void kernel_launch(void* const* d_in, const int* in_sizes, int n_in,
                              void* d_out, int out_size, void* d_ws, size_t ws_size,
                              hipStream_t stream) {
    const float* emb  = (const float*)d_in[0];     // (100000, 50) fp32
    const int2*  prs  = (const int2*)d_in[1];      // (2000000, 2) int32
    int n_pairs = in_sizes[1] / 2;
    int n_rows  = in_sizes[0] / (2 * DIMS);

    float*    ws     = (float*)d_ws;                // ws[0]=acc, ws[1]=ticket
    unsigned* ticket = (unsigned*)(ws + 1);
    float*    out    = (float*)d_out;
    float2*   keys   = (float2*)((char*)d_ws + 256);            // 8B * n_rows
    unsigned* gpack  = (unsigned*)(keys + n_rows);              // packed codes
    // gpack byte offset = 256 + 8*n_rows: 16B-aligned for even n_rows.

    const int    packWords = (n_rows + 4) / 5;
    const size_t packPad   = ((size_t)packWords * 4 + 15) & ~(size_t)15;  // 80000 B
    const bool ws_ok = (ws_size >= 256 + (size_t)n_rows * 8 + packPad + 64) &&
                       ((n_rows & 1) == 0);
    const bool path_ok = ws_ok && (packPad + 512 <= 160 * 1024);

    if (path_ok) {
        const int n_tiles = (n_rows + TROWS - 1) / TROWS;
        hipLaunchKernelGGL(repack6_kernel, dim3(min(n_tiles, 2048)), dim3(256),
                           0, stream, emb, keys, gpack, n_rows, ws, ticket);
        hipLaunchKernelGGL(screen6_kernel, dim3(512), dim3(SBLK),
                           packPad, stream,
                           keys, gpack, emb, prs, n_pairs, n_rows, ws, ticket, out);
    } else {
        hipLaunchKernelGGL(init_ws_kernel, dim3(1), dim3(64), 0, stream, ws);
        hipLaunchKernelGGL(nf1_fallback_kernel, dim3(4096), dim3(256), 0, stream,
                           emb, prs, n_pairs, ws);
        hipLaunchKernelGGL(fallback_finalize_kernel, dim3(1), dim3(64), 0, stream, ws, out);
    }
}